// Round 1
// baseline (665.385 us; speedup 1.0000x reference)
//
#include <hip/hip_runtime.h>
#include <hip/hip_bf16.h>
#include <cstdint>

#define IN_DIMX 768
#define NTAGS 50
#define NCC 52
#define LSEQ 512
#define BATCH 64
#define START_TAG 50
#define END_TAG 51
#define NEGV (-1000000000.0f)
#define LOG2E 1.4426950408889634f
#define LN2 0.6931471805599453f

// ---------------- GEMM: logits[(b*L+t)*64 + j] = x[b,t,:] . W[j,:] + bias[j] ----
#define BM 64
#define BN 64
#define BKC 64
#define LDSP (BM + 4)   // stride 68 floats: 16B-aligned float4 rows, mild write conflicts only

__global__ __launch_bounds__(256) void gemm_logits(
    const float* __restrict__ x, const float* __restrict__ W,
    const float* __restrict__ bias, float* __restrict__ outL)
{
  __shared__ float xs[BKC][LDSP];   // [k][m]
  __shared__ float ws[BKC][LDSP];   // [k][n]
  const int tid = threadIdx.x;
  const int bx = blockIdx.x;
  const size_t row0 = (size_t)bx * BM;
  const int ty = tid >> 4, tx = tid & 15;   // 16x16 thread grid, 4x4 outputs each
  const int lr = tid >> 4, lk = tid & 15;   // staging: row group, float4 index along k
  float acc[4][4] = {};

  for (int kc = 0; kc < IN_DIMX; kc += BKC) {
    #pragma unroll
    for (int rr = 0; rr < 4; ++rr) {
      const int r = lr + rr * 16;
      const float4 v = *reinterpret_cast<const float4*>(&x[(row0 + r) * IN_DIMX + kc + lk * 4]);
      xs[lk*4+0][r] = v.x; xs[lk*4+1][r] = v.y; xs[lk*4+2][r] = v.z; xs[lk*4+3][r] = v.w;
    }
    #pragma unroll
    for (int rr = 0; rr < 4; ++rr) {
      const int c = lr + rr * 16;
      float4 v = make_float4(0.f, 0.f, 0.f, 0.f);
      if (c < NTAGS) v = *reinterpret_cast<const float4*>(&W[c * IN_DIMX + kc + lk * 4]);
      ws[lk*4+0][c] = v.x; ws[lk*4+1][c] = v.y; ws[lk*4+2][c] = v.z; ws[lk*4+3][c] = v.w;
    }
    __syncthreads();
    #pragma unroll
    for (int kk = 0; kk < BKC; ++kk) {
      const float4 a  = *reinterpret_cast<const float4*>(&xs[kk][ty * 4]);
      const float4 bq = *reinterpret_cast<const float4*>(&ws[kk][tx * 4]);
      acc[0][0] += a.x*bq.x; acc[0][1] += a.x*bq.y; acc[0][2] += a.x*bq.z; acc[0][3] += a.x*bq.w;
      acc[1][0] += a.y*bq.x; acc[1][1] += a.y*bq.y; acc[1][2] += a.y*bq.z; acc[1][3] += a.y*bq.w;
      acc[2][0] += a.z*bq.x; acc[2][1] += a.z*bq.y; acc[2][2] += a.z*bq.z; acc[2][3] += a.z*bq.w;
      acc[3][0] += a.w*bq.x; acc[3][1] += a.w*bq.y; acc[3][2] += a.w*bq.z; acc[3][3] += a.w*bq.w;
    }
    __syncthreads();
  }
  #pragma unroll
  for (int i = 0; i < 4; ++i) {
    const int r = ty * 4 + i;
    const int c = tx * 4;
    float4 o;
    o.x = acc[i][0] + ((c + 0) < NTAGS ? bias[c + 0] : 0.f);
    o.y = acc[i][1] + ((c + 1) < NTAGS ? bias[c + 1] : 0.f);
    o.z = acc[i][2] + ((c + 2) < NTAGS ? bias[c + 2] : 0.f);
    o.w = acc[i][3] + ((c + 3) < NTAGS ? bias[c + 3] : 0.f);
    *reinterpret_cast<float4*>(&outL[(row0 + r) * 64 + c]) = o;
  }
}

// ---------------- forward scan + path score, one block per batch -------------
// lane j (0..51) owns output tag j; wave w owns i-chunk [13w, 13w+13).
// All math in base-2 scale (values pre-multiplied by log2(e)) so v_exp_f32 /
// v_log_f32 apply directly. alpha kept redundantly in registers of every wave.
__device__ __forceinline__ float lane_bcast(float v, int lane) {
  return __int_as_float(__builtin_amdgcn_readlane(__float_as_int(v), lane));
}

__global__ __launch_bounds__(256) void crf_scan(
    const float* __restrict__ logits, const int* __restrict__ y,
    const int* __restrict__ lengths, const float* __restrict__ T,
    float* __restrict__ out)
{
  __shared__ float Traw[NCC * NCC];
  __shared__ float part[2][4][64][2];  // [buf][wave][lane][m,s] double-buffered
  __shared__ float red[256];
  const int b = blockIdx.x;
  const int tid = threadIdx.x;
  const int w = tid >> 6;
  const int j = tid & 63;
  const int jj = (j < NCC - 1) ? j : (NCC - 1);  // clamp idle lanes 52..63

  for (int idx = tid; idx < NCC * NCC; idx += 256) Traw[idx] = T[idx];
  __syncthreads();

  int len = lengths[b];
  if (len < 1) len = 1;

  float Treg[13];
  const int i0 = w * 13;
  #pragma unroll
  for (int r = 0; r < 13; ++r) Treg[r] = Traw[(i0 + r) * NCC + jj] * LOG2E;

  float alpha = (j == START_TAG) ? 0.0f : NEGV * LOG2E;  // scaled space

  const float* lrow = logits + (size_t)b * LSEQ * 64;
  const float eneg = NEGV * LOG2E;
  float eNext = (jj < NTAGS) ? lrow[jj] * LOG2E : eneg;

  for (int t = 0; t < len; ++t) {
    const float e = eNext;
    if (t + 1 < len) eNext = (jj < NTAGS) ? lrow[(t + 1) * 64 + jj] * LOG2E : eneg;

    float cand[13];
    #pragma unroll
    for (int r = 0; r < 13; ++r)
      cand[r] = lane_bcast(alpha, i0 + r) + Treg[r];

    // tree max over 13
    float m0 = fmaxf(cand[0], cand[1]);
    float m1 = fmaxf(cand[2], cand[3]);
    float m2 = fmaxf(cand[4], cand[5]);
    float m3 = fmaxf(cand[6], cand[7]);
    float m4 = fmaxf(cand[8], cand[9]);
    float m5 = fmaxf(cand[10], cand[11]);
    const float m = fmaxf(fmaxf(fmaxf(m0, m1), fmaxf(m2, m3)),
                          fmaxf(fmaxf(m4, m5), cand[12]));
    // tree sum of exp2
    float q0 = exp2f(cand[0] - m), q1 = exp2f(cand[1] - m), q2 = exp2f(cand[2] - m);
    float q3 = exp2f(cand[3] - m), q4 = exp2f(cand[4] - m), q5 = exp2f(cand[5] - m);
    float q6 = exp2f(cand[6] - m), q7 = exp2f(cand[7] - m), q8 = exp2f(cand[8] - m);
    float q9 = exp2f(cand[9] - m), q10 = exp2f(cand[10] - m), q11 = exp2f(cand[11] - m);
    float q12 = exp2f(cand[12] - m);
    const float s = ((q0 + q1) + (q2 + q3)) + ((q4 + q5) + (q6 + q7))
                  + (((q8 + q9) + (q10 + q11)) + q12);

    const int buf = t & 1;
    part[buf][w][j][0] = m;
    part[buf][w][j][1] = s;
    __syncthreads();
    const float pm0 = part[buf][0][j][0], ps0 = part[buf][0][j][1];
    const float pm1 = part[buf][1][j][0], ps1 = part[buf][1][j][1];
    const float pm2 = part[buf][2][j][0], ps2 = part[buf][2][j][1];
    const float pm3 = part[buf][3][j][0], ps3 = part[buf][3][j][1];
    const float M = fmaxf(fmaxf(pm0, pm1), fmaxf(pm2, pm3));
    const float S = ps0 * exp2f(pm0 - M) + ps1 * exp2f(pm1 - M)
                  + ps2 * exp2f(pm2 - M) + ps3 * exp2f(pm3 - M);
    alpha = e + M + log2f(S);
    // no second barrier: next step writes the other buffer; write-after-read of
    // this buffer only happens after the NEXT step's barrier.
  }

  // all_path = LSE_j(alpha + T[j,END]) (scaled space -> * ln2)
  float v = (j < NCC) ? (alpha + Traw[jj * NCC + END_TAG] * LOG2E) : -3.0e38f;
  float Mv = v;
  #pragma unroll
  for (int off = 32; off > 0; off >>= 1) Mv = fmaxf(Mv, __shfl_xor(Mv, off, 64));
  float sv = (j < NCC) ? exp2f(v - Mv) : 0.f;
  #pragma unroll
  for (int off = 32; off > 0; off >>= 1) sv += __shfl_xor(sv, off, 64);
  const float all_path = (Mv + log2f(sv)) * LN2;

  // path score: T[START,y0] + sum_{t<len} logit[t,y_t] + sum_{1<=t<len} T[y_{t-1},y_t]
  //             + T[y_{len-1}, END]
  const int* yb = y + b * LSEQ;
  float ps = 0.f;
  for (int t = tid; t < len; t += 256) {
    const int yt = yb[t];
    ps += lrow[t * 64 + yt];
    if (t >= 1) ps += Traw[yb[t - 1] * NCC + yt];
  }
  red[tid] = ps;
  __syncthreads();
  #pragma unroll
  for (int s2 = 128; s2 > 0; s2 >>= 1) {
    if (tid < s2) red[tid] += red[tid + s2];
    __syncthreads();
  }
  if (tid == 0) {
    const float path = red[0] + Traw[START_TAG * NCC + yb[0]]
                     + Traw[yb[len - 1] * NCC + END_TAG];
    atomicAdd(out, (all_path - path) * (1.0f / BATCH));
  }
}

__global__ void zero_out_k(float* o) { o[0] = 0.f; }

extern "C" void kernel_launch(void* const* d_in, const int* in_sizes, int n_in,
                              void* d_out, int out_size, void* d_ws, size_t ws_size,
                              hipStream_t stream) {
  const float* x       = (const float*)d_in[0];
  const int*   y       = (const int*)d_in[1];
  const int*   lengths = (const int*)d_in[2];
  const float* W       = (const float*)d_in[3];
  const float* bias    = (const float*)d_in[4];
  const float* T       = (const float*)d_in[5];
  float* outp   = (float*)d_out;
  float* logits = (float*)d_ws;   // [BATCH*LSEQ][64] padded fp32, 8.4 MB

  zero_out_k<<<1, 1, 0, stream>>>(outp);
  gemm_logits<<<(BATCH * LSEQ) / BM, 256, 0, stream>>>(x, W, bias, logits);
  crf_scan<<<BATCH, 256, 0, stream>>>(logits, y, lengths, T, outp);
}

// Round 3
// 463.338 us; speedup vs baseline: 1.4361x; 1.4361x over previous
//
#include <hip/hip_runtime.h>
#include <hip/hip_bf16.h>
#include <cstdint>

#define IN_DIMX 768
#define NTAGS 50
#define NCC 52
#define LSEQ 512
#define BATCH 64
#define START_TAG 50
#define END_TAG 51
#define NEGV (-1000000000.0f)
#define LOG2E 1.4426950408889634f
#define LN2 0.6931471805599453f

// ---------------- GEMM: logits[(b*L+t)*64 + j] = x[b,t,:] . W[j,:] + bias[j] ----
#define BM 64
#define BN 64
#define BKC 64
#define LDSP (BM + 4)

__global__ __launch_bounds__(256) void gemm_logits(
    const float* __restrict__ x, const float* __restrict__ W,
    const float* __restrict__ bias, float* __restrict__ outL)
{
  __shared__ float xs[BKC][LDSP];   // [k][m]
  __shared__ float ws[BKC][LDSP];   // [k][n]
  const int tid = threadIdx.x;
  const int bx = blockIdx.x;
  const size_t row0 = (size_t)bx * BM;
  const int ty = tid >> 4, tx = tid & 15;
  const int lr = tid >> 4, lk = tid & 15;
  float acc[4][4] = {};

  for (int kc = 0; kc < IN_DIMX; kc += BKC) {
    #pragma unroll
    for (int rr = 0; rr < 4; ++rr) {
      const int r = lr + rr * 16;
      const float4 v = *reinterpret_cast<const float4*>(&x[(row0 + r) * IN_DIMX + kc + lk * 4]);
      xs[lk*4+0][r] = v.x; xs[lk*4+1][r] = v.y; xs[lk*4+2][r] = v.z; xs[lk*4+3][r] = v.w;
    }
    #pragma unroll
    for (int rr = 0; rr < 4; ++rr) {
      const int c = lr + rr * 16;
      float4 v = make_float4(0.f, 0.f, 0.f, 0.f);
      if (c < NTAGS) v = *reinterpret_cast<const float4*>(&W[c * IN_DIMX + kc + lk * 4]);
      ws[lk*4+0][c] = v.x; ws[lk*4+1][c] = v.y; ws[lk*4+2][c] = v.z; ws[lk*4+3][c] = v.w;
    }
    __syncthreads();
    #pragma unroll
    for (int kk = 0; kk < BKC; ++kk) {
      const float4 a  = *reinterpret_cast<const float4*>(&xs[kk][ty * 4]);
      const float4 bq = *reinterpret_cast<const float4*>(&ws[kk][tx * 4]);
      acc[0][0] += a.x*bq.x; acc[0][1] += a.x*bq.y; acc[0][2] += a.x*bq.z; acc[0][3] += a.x*bq.w;
      acc[1][0] += a.y*bq.x; acc[1][1] += a.y*bq.y; acc[1][2] += a.y*bq.z; acc[1][3] += a.y*bq.w;
      acc[2][0] += a.z*bq.x; acc[2][1] += a.z*bq.y; acc[2][2] += a.z*bq.z; acc[2][3] += a.z*bq.w;
      acc[3][0] += a.w*bq.x; acc[3][1] += a.w*bq.y; acc[3][2] += a.w*bq.z; acc[3][3] += a.w*bq.w;
    }
    __syncthreads();
  }
  #pragma unroll
  for (int i = 0; i < 4; ++i) {
    const int r = ty * 4 + i;
    const int c = tx * 4;
    float4 o;
    o.x = acc[i][0] + ((c + 0) < NTAGS ? bias[c + 0] : 0.f);
    o.y = acc[i][1] + ((c + 1) < NTAGS ? bias[c + 1] : 0.f);
    o.z = acc[i][2] + ((c + 2) < NTAGS ? bias[c + 2] : 0.f);
    o.w = acc[i][3] + ((c + 3) < NTAGS ? bias[c + 3] : 0.f);
    *reinterpret_cast<float4*>(&outL[(row0 + r) * 64 + c]) = o;
  }
}

// ---------------- forward scan in probability space, 1 wave per batch --------
// p[j] = 2^(alpha[j]*log2e - Mc).  Recurrence: p' = (p . E) * exp2(e*log2e) * r
// with E[i][j] = 2^(T[i][j]*log2e) held in registers (lane j owns column j),
// r = lag-1 rescale = 1/p[0];  Mc -= log2(r) keeps the exact log offset
// (same r value in both places -> representation stays consistent).
// No LDS, no barriers; critical path = 52 readlane + 52 fmac per step.
__device__ __forceinline__ float lane_bcast(float v, int lane) {
  return __int_as_float(__builtin_amdgcn_readlane(__float_as_int(v), lane));
}

__global__ __launch_bounds__(64) void crf_scan(
    const float* __restrict__ logits, const int* __restrict__ y,
    const int* __restrict__ lengths, const float* __restrict__ T,
    float* __restrict__ out)
{
  const int b = blockIdx.x;
  const int j = threadIdx.x;                 // 0..63
  const int jj = (j < NCC) ? j : (NCC - 1);
  const bool act = (j < NCC);
  const bool emit = (j < NTAGS);

  // E column for my tag j (exp2 of scaled T); 0 for idle lanes so they never
  // contribute to sums.  exp2f(-1e9*log2e) underflows to exactly 0 -> the
  // NEG sentinels (column START, row END) behave identically to the reference.
  float E[NCC];
  #pragma unroll
  for (int i = 0; i < NCC; ++i) {
    const float tv = T[i * NCC + jj];
    E[i] = act ? exp2f(tv * LOG2E) : 0.f;
  }
  const float E2 = act ? exp2f(T[jj * NCC + END_TAG] * LOG2E) : 0.f;

  int len = lengths[b]; if (len < 1) len = 1;
  const float* lrow = logits + (size_t)b * LSEQ * 64;

  float p  = (j == START_TAG) ? 1.f : 0.f;   // alpha0 in prob space
  float Mc = 0.f;                            // accumulated log2 scale
  float r  = 1.f;                            // lag-1 rescale factor
  float sCur = emit ? exp2f(lrow[j] * LOG2E) : 0.f;   // exp2 of emission, t=0

  for (int t = 0; t < len; ++t) {
    const int tn = (t + 1 < len) ? (t + 1) : t;
    const float eN = emit ? lrow[tn * 64 + j] : 0.f;  // prefetch next emission
    const float scale = sCur * r;                      // off critical path

    float q0 = 0.f, q1 = 0.f, q2 = 0.f, q3 = 0.f;
    #pragma unroll
    for (int i = 0; i < NCC; i += 4) {
      q0 = fmaf(lane_bcast(p, i + 0), E[i + 0], q0);
      q1 = fmaf(lane_bcast(p, i + 1), E[i + 1], q1);
      q2 = fmaf(lane_bcast(p, i + 2), E[i + 2], q2);
      q3 = fmaf(lane_bcast(p, i + 3), E[i + 3], q3);
    }
    const float q = (q0 + q1) + (q2 + q3);
    p = q * scale;

    Mc -= log2f(r);                           // r applied this step (uniform)
    const float p0 = lane_bcast(p, 0);        // lane 0 finite & >0 for all t
    r = 1.0f / p0;                            // off critical path (used next
                                              // step after the dot product)
    sCur = emit ? exp2f(eN * LOG2E) : 0.f;
  }

  // all_path = ln2 * (Mc + log2(sum_j p_j * E2_j))
  float v = p * E2;
  #pragma unroll
  for (int off = 32; off; off >>= 1) v += __shfl_xor(v, off, 64);
  const float all_path = (Mc + log2f(v)) * LN2;

  // path score (raw T, raw logits)
  const int* yb = y + b * LSEQ;
  float ps = 0.f;
  for (int t = j; t < len; t += 64) {
    const int yt = yb[t];
    ps += lrow[t * 64 + yt];
    if (t >= 1) ps += T[yb[t - 1] * NCC + yt];
  }
  #pragma unroll
  for (int off = 32; off; off >>= 1) ps += __shfl_xor(ps, off, 64);

  if (j == 0) {
    const float path = ps + T[START_TAG * NCC + yb[0]]
                     + T[yb[len - 1] * NCC + END_TAG];
    atomicAdd(out, (all_path - path) * (1.0f / BATCH));
  }
}

__global__ void zero_out_k(float* o) { o[0] = 0.f; }

extern "C" void kernel_launch(void* const* d_in, const int* in_sizes, int n_in,
                              void* d_out, int out_size, void* d_ws, size_t ws_size,
                              hipStream_t stream) {
  const float* x       = (const float*)d_in[0];
  const int*   y       = (const int*)d_in[1];
  const int*   lengths = (const int*)d_in[2];
  const float* W       = (const float*)d_in[3];
  const float* bias    = (const float*)d_in[4];
  const float* T       = (const float*)d_in[5];
  float* outp   = (float*)d_out;
  float* logits = (float*)d_ws;   // [BATCH*LSEQ][64] fp32, 8.4 MB

  zero_out_k<<<1, 1, 0, stream>>>(outp);
  gemm_logits<<<(BATCH * LSEQ) / BM, 256, 0, stream>>>(x, W, bias, logits);
  crf_scan<<<BATCH, 64, 0, stream>>>(logits, y, lengths, T, outp);
}